// Round 1
// baseline (1755.891 us; speedup 1.0000x reference)
//
#include <hip/hip_runtime.h>
#include <cstdint>
#include <cstddef>

// ---------------- CSR build ----------------
__global__ void count_kernel(const int* __restrict__ rows, int* __restrict__ counts, int E) {
    int e = blockIdx.x * blockDim.x + threadIdx.x;
    if (e < E) atomicAdd(&counts[rows[e]], 1);
}

__global__ void scan_kernel(const int* __restrict__ counts, int* __restrict__ rp, int n) {
    __shared__ int sm[1024];
    int carry = 0;
    for (int base = 0; base < n; base += 1024) {
        int i = base + (int)threadIdx.x;
        int v = (i < n) ? counts[i] : 0;
        sm[threadIdx.x] = v;
        __syncthreads();
        for (int off = 1; off < 1024; off <<= 1) {
            int t = ((int)threadIdx.x >= off) ? sm[threadIdx.x - off] : 0;
            __syncthreads();
            sm[threadIdx.x] += t;
            __syncthreads();
        }
        if (i < n) rp[i + 1] = carry + sm[threadIdx.x];
        int tot = sm[1023];
        __syncthreads();
        carry += tot;
    }
    if (threadIdx.x == 0) rp[0] = 0;
}

__global__ void scatter_kernel(const int* __restrict__ rows, const int* __restrict__ cols,
                               const float* __restrict__ avals,
                               const int* __restrict__ rp, int* __restrict__ cursor,
                               int* __restrict__ col_s, float* __restrict__ a_s, int E) {
    int e = blockIdx.x * blockDim.x + threadIdx.x;
    if (e < E) {
        int r = rows[e];
        int pos = rp[r] + atomicAdd(&cursor[r], 1);
        col_s[pos] = cols[e];
        a_s[pos]   = avals[e];
    }
}

// ---------------- small utils ----------------
__global__ void transpose_kernel(const float* __restrict__ W, float* __restrict__ Wt,
                                 int rows, int cols) {
    int idx = blockIdx.x * blockDim.x + threadIdx.x;
    if (idx < rows * cols) {
        int r = idx / cols, c = idx % cols;
        Wt[(size_t)c * rows + r] = W[idx];
    }
}

__global__ void copy4_kernel(const float* __restrict__ src, float* __restrict__ dst, int n4) {
    int i = blockIdx.x * blockDim.x + threadIdx.x;
    if (i < n4) ((float4*)dst)[i] = ((const float4*)src)[i];
}

// ---------------- fp32 NT GEMM: C[M,Dout] = A[M,K] @ B[Dout,K]^T + bias ----------------
// 64x64 tile, BK=16, 256 threads, 4x4 micro-tile.
__global__ __launch_bounds__(256) void gemm_nt(const float* __restrict__ A,
                                               const float* __restrict__ B,
                                               const float* __restrict__ bias,
                                               float* __restrict__ C,
                                               int M, int K, int Dout) {
    __shared__ float As[16][64];
    __shared__ float Bs[16][64];
    int bm = blockIdx.y * 64;
    int bn = blockIdx.x * 64;
    int tid = threadIdx.x;
    int tx = tid & 15, ty = tid >> 4;
    int lr = tid >> 2;          // 0..63 (row within tile to load)
    int lk = (tid & 3) * 4;     // 0,4,8,12 (k offset to load)
    float acc[4][4] = {};
    for (int k0 = 0; k0 < K; k0 += 16) {
        float4 va = make_float4(0.f, 0.f, 0.f, 0.f);
        int gr = bm + lr;
        if (gr < M) va = *(const float4*)(A + (size_t)gr * K + k0 + lk);
        float4 vb = *(const float4*)(B + (size_t)(bn + lr) * K + k0 + lk);
        As[lk + 0][lr] = va.x; As[lk + 1][lr] = va.y; As[lk + 2][lr] = va.z; As[lk + 3][lr] = va.w;
        Bs[lk + 0][lr] = vb.x; Bs[lk + 1][lr] = vb.y; Bs[lk + 2][lr] = vb.z; Bs[lk + 3][lr] = vb.w;
        __syncthreads();
#pragma unroll
        for (int k = 0; k < 16; ++k) {
            float4 a4 = *(const float4*)&As[k][ty * 4];
            float4 b4 = *(const float4*)&Bs[k][tx * 4];
            float a[4] = {a4.x, a4.y, a4.z, a4.w};
            float b[4] = {b4.x, b4.y, b4.z, b4.w};
#pragma unroll
            for (int i = 0; i < 4; ++i)
#pragma unroll
                for (int j = 0; j < 4; ++j)
                    acc[i][j] += a[i] * b[j];
        }
        __syncthreads();
    }
    float bv[4] = {0.f, 0.f, 0.f, 0.f};
    if (bias) {
#pragma unroll
        for (int j = 0; j < 4; ++j) bv[j] = bias[bn + tx * 4 + j];
    }
#pragma unroll
    for (int i = 0; i < 4; ++i) {
        int gr = bm + ty * 4 + i;
        if (gr < M) {
            float4 o = make_float4(acc[i][0] + bv[0], acc[i][1] + bv[1],
                                   acc[i][2] + bv[2], acc[i][3] + bv[3]);
            *(float4*)(C + (size_t)gr * Dout + bn + tx * 4) = o;
        }
    }
}

// ---------------- f1/f2 = M @ va, M @ vb (one wave per node) ----------------
__global__ void fvec_kernel(const float* __restrict__ Mm, const float* __restrict__ va,
                            const float* __restrict__ vb, float* __restrict__ f1,
                            float* __restrict__ f2, int d) {
    int n = blockIdx.x;
    int lane = threadIdx.x;
    const float* row = Mm + (size_t)n * d;
    float s1 = 0.f, s2 = 0.f;
    for (int k = lane; k < d; k += 64) {
        float m = row[k];
        s1 += m * va[k];
        s2 += m * vb[k];
    }
#pragma unroll
    for (int off = 32; off > 0; off >>= 1) {
        s1 += __shfl_xor(s1, off);
        s2 += __shfl_xor(s2, off);
    }
    if (lane == 0) { f1[n] = s1; f2[n] = s2; }
}

// ---------------- edge softmax of sigmoid(logits), one wave per row ----------------
__global__ void att_kernel(const int* __restrict__ rp, const int* __restrict__ col_s,
                           const float* __restrict__ a_s, const float* __restrict__ f1,
                           const float* __restrict__ f2, float* __restrict__ att) {
    int r = blockIdx.x;
    int lane = threadIdx.x;
    int beg = rp[r], end = rp[r + 1];
    if (beg == end) return;
    float fr = f1[r];
    float m = -1e30f;
    for (int j = beg + lane; j < end; j += 64) {
        float x = a_s[j] * (fr + f2[col_s[j]]);
        float v = 1.f / (1.f + __expf(-x));
        att[j] = v;
        m = fmaxf(m, v);
    }
#pragma unroll
    for (int off = 32; off > 0; off >>= 1) m = fmaxf(m, __shfl_xor(m, off));
    float s = 0.f;
    for (int j = beg + lane; j < end; j += 64) {
        float e = __expf(att[j] - m);
        att[j] = e;
        s += e;
    }
#pragma unroll
    for (int off = 32; off > 0; off >>= 1) s += __shfl_xor(s, off);
    float inv = 1.f / s;
    for (int j = beg + lane; j < end; j += 64) att[j] *= inv;
}

// ---------------- SpMM (CSR gather): C[r,:] = sum_j att[j] * H[col[j],:] ----------------
// blockDim = d/4 (lane owns one float4 of the feature dim)
__global__ void spmm_kernel(const int* __restrict__ rp, const int* __restrict__ col_s,
                            const float* __restrict__ att, const float* __restrict__ H,
                            float* __restrict__ C, int d4) {
    int r = blockIdx.x;
    int lane = threadIdx.x;
    int beg = rp[r], end = rp[r + 1];
    float4 acc = make_float4(0.f, 0.f, 0.f, 0.f);
    const float4* H4 = (const float4*)H;
    for (int j = beg; j < end; ++j) {
        int c = col_s[j];
        float w = att[j];
        float4 h = H4[(size_t)c * d4 + lane];
        acc.x += w * h.x; acc.y += w * h.y; acc.z += w * h.z; acc.w += w * h.w;
    }
    ((float4*)C)[(size_t)r * d4 + lane] = acc;
}

// ---------------- driver ----------------
extern "C" void kernel_launch(void* const* d_in, const int* in_sizes, int n_in,
                              void* d_out, int out_size, void* d_ws, size_t ws_size,
                              hipStream_t stream) {
    const float* X    = (const float*)d_in[0];
    const int*   erow = (const int*)d_in[1];
    const int*   ecol = (const int*)d_in[2];
    const float* aval = (const float*)d_in[3];
    const float* W0   = (const float*)d_in[4];
    const float* b0   = (const float*)d_in[5];
    const float* W1   = (const float*)d_in[6];
    const float* b1   = (const float*)d_in[7];
    const float* v00  = (const float*)d_in[8];
    const float* v01  = (const float*)d_in[9];
    const float* v10  = (const float*)d_in[10];
    const float* v11  = (const float*)d_in[11];

    const int D0 = 512, D1 = 256, D2 = 128;
    const int N = in_sizes[0] / D0;
    const int E = in_sizes[1];
    float* out = (float*)d_out;

    float* ws = (float*)d_ws;
    size_t off = 0;
    auto alloc = [&](size_t nfl) { float* p = ws + off; off += (nfl + 63) & ~(size_t)63; return p; };
    float* bufA = alloc((size_t)N * D1);   // M0 / T1 / T3
    float* bufB = alloc((size_t)N * D1);   // H1 / T2
    float* bufC = alloc((size_t)N * D2);   // M1
    float* bufD = alloc((size_t)N * D2);   // H2 (final_H)
    float* att0 = alloc(E);
    float* att1 = alloc(E);
    float* a_s  = alloc(E);
    float* f1   = alloc(N);
    float* f2   = alloc(N);
    float* Wt1  = alloc((size_t)D1 * D2);  // W1^T [256,128]
    float* Wt0  = alloc((size_t)D0 * D1);  // W0^T [512,256]
    int* rp     = (int*)alloc(N + 1);
    int* cursor = (int*)alloc(N);
    int* col_s  = (int*)alloc(E);

    // ---- CSR build (rows sorted) ----
    hipMemsetAsync(cursor, 0, (size_t)N * sizeof(int), stream);
    count_kernel<<<(E + 255) / 256, 256, 0, stream>>>(erow, cursor, E);
    scan_kernel<<<1, 1024, 0, stream>>>(cursor, rp, N);
    hipMemsetAsync(cursor, 0, (size_t)N * sizeof(int), stream);
    scatter_kernel<<<(E + 255) / 256, 256, 0, stream>>>(erow, ecol, aval, rp, cursor, col_s, a_s, E);

    // ---- weight transposes for the decoder (NN -> NT form) ----
    transpose_kernel<<<(D2 * D1 + 255) / 256, 256, 0, stream>>>(W1, Wt1, D2, D1);
    transpose_kernel<<<(D1 * D0 + 255) / 256, 256, 0, stream>>>(W0, Wt0, D1, D0);

    const int gy = (N + 63) / 64;

    // ---- encoder layer 0 ----
    gemm_nt<<<dim3(D1 / 64, gy), 256, 0, stream>>>(X, W0, b0, bufA, N, D0, D1);      // M0
    fvec_kernel<<<N, 64, 0, stream>>>(bufA, v00, v01, f1, f2, D1);
    att_kernel<<<N, 64, 0, stream>>>(rp, col_s, a_s, f1, f2, att0);
    spmm_kernel<<<N, D1 / 4, 0, stream>>>(rp, col_s, att0, bufA, bufB, D1 / 4);      // H1

    // ---- encoder layer 1 ----
    gemm_nt<<<dim3(D2 / 64, gy), 256, 0, stream>>>(bufB, W1, b1, bufC, N, D1, D2);   // M1
    fvec_kernel<<<N, 64, 0, stream>>>(bufC, v10, v11, f1, f2, D2);
    att_kernel<<<N, 64, 0, stream>>>(rp, col_s, a_s, f1, f2, att1);
    spmm_kernel<<<N, D2 / 4, 0, stream>>>(rp, col_s, att1, bufC, bufD, D2 / 4);      // H2 = final_H

    // final_H -> out tail
    copy4_kernel<<<((N * (size_t)D2 / 4) + 255) / 256, 256, 0, stream>>>(
        bufD, out + (size_t)N * D0, (int)((size_t)N * D2 / 4));

    // ---- decoder (reordered: out = spmm(att0, spmm(att1, H2@W1)) @ W0) ----
    gemm_nt<<<dim3(D1 / 64, gy), 256, 0, stream>>>(bufD, Wt1, nullptr, bufA, N, D2, D1); // T1
    spmm_kernel<<<N, D1 / 4, 0, stream>>>(rp, col_s, att1, bufA, bufB, D1 / 4);          // T2
    spmm_kernel<<<N, D1 / 4, 0, stream>>>(rp, col_s, att0, bufB, bufA, D1 / 4);          // T3
    gemm_nt<<<dim3(D0 / 64, gy), 256, 0, stream>>>(bufA, Wt0, nullptr, out, N, D1, D0);  // out = T3@W0
}

// Round 2
// 1220.138 us; speedup vs baseline: 1.4391x; 1.4391x over previous
//
#include <hip/hip_runtime.h>
#include <cstdint>
#include <cstddef>

typedef __attribute__((ext_vector_type(8))) short bf16x8;
typedef __attribute__((ext_vector_type(4))) float f32x4;

__device__ __forceinline__ ushort f2b(float f) {
    union { float f; uint32_t u; } v; v.f = f;
    uint32_t r = (v.u + 0x7fffu + ((v.u >> 16) & 1u)) >> 16;
    return (ushort)r;
}
__device__ __forceinline__ float b2f(ushort b) {
    union { uint32_t u; float f; } v; v.u = ((uint32_t)b) << 16;
    return v.f;
}

// ---------------- CSR build ----------------
__global__ void count_kernel(const int* __restrict__ rows, int* __restrict__ counts, int E) {
    int e = blockIdx.x * blockDim.x + threadIdx.x;
    if (e < E) atomicAdd(&counts[rows[e]], 1);
}

__global__ void scan_kernel(const int* __restrict__ counts, int* __restrict__ rp, int n) {
    __shared__ int sm[1024];
    int carry = 0;
    for (int base = 0; base < n; base += 1024) {
        int i = base + (int)threadIdx.x;
        int v = (i < n) ? counts[i] : 0;
        sm[threadIdx.x] = v;
        __syncthreads();
        for (int off = 1; off < 1024; off <<= 1) {
            int t = ((int)threadIdx.x >= off) ? sm[threadIdx.x - off] : 0;
            __syncthreads();
            sm[threadIdx.x] += t;
            __syncthreads();
        }
        if (i < n) rp[i + 1] = carry + sm[threadIdx.x];
        int tot = sm[1023];
        __syncthreads();
        carry += tot;
    }
    if (threadIdx.x == 0) rp[0] = 0;
}

__global__ void scatter_kernel(const int* __restrict__ rows, const int* __restrict__ cols,
                               const float* __restrict__ avals,
                               const int* __restrict__ rp, int* __restrict__ cursor,
                               int* __restrict__ col_s, float* __restrict__ a_s, int E) {
    int e = blockIdx.x * blockDim.x + threadIdx.x;
    if (e < E) {
        int r = rows[e];
        int pos = rp[r] + atomicAdd(&cursor[r], 1);
        col_s[pos] = cols[e];
        a_s[pos]   = avals[e];
    }
}

// ---------------- fp32 -> bf16 converts ----------------
__global__ void f2b4_kernel(const float* __restrict__ src, ushort* __restrict__ dst, int n4) {
    int i = blockIdx.x * blockDim.x + threadIdx.x;
    if (i < n4) {
        float4 v = ((const float4*)src)[i];
        ushort4 o;
        o.x = f2b(v.x); o.y = f2b(v.y); o.z = f2b(v.z); o.w = f2b(v.w);
        ((ushort4*)dst)[i] = o;
    }
}

__global__ void transpose_f2b_kernel(const float* __restrict__ W, ushort* __restrict__ Wt,
                                     int rows, int cols) {
    int idx = blockIdx.x * blockDim.x + threadIdx.x;
    if (idx < rows * cols) {
        int r = idx / cols, c = idx % cols;
        Wt[(size_t)c * rows + r] = f2b(W[idx]);
    }
}

// ---------------- bf16 MFMA NT GEMM ----------------
// C[M,Dout] = A[M,K] @ B[Dout,K]^T + bias.  A,B bf16 row-major (K contiguous).
// 128x128 block tile, 256 threads = 4 waves, each wave a 64x64 quadrant (4x4 MFMA frags).
// Writes fp32 (Cf) and/or bf16 (Ch).
__global__ __launch_bounds__(256) void gemm_bf16(const ushort* __restrict__ A,
                                                 const ushort* __restrict__ B,
                                                 const float* __restrict__ bias,
                                                 float* __restrict__ Cf,
                                                 ushort* __restrict__ Ch,
                                                 int M, int K, int Dout) {
    __shared__ ushort As[128][40];   // +8 pad breaks bank aliasing on frag reads
    __shared__ ushort Bs[128][40];
    int bm = blockIdx.y * 128, bn = blockIdx.x * 128;
    int tid = threadIdx.x;
    int w = tid >> 6, l = tid & 63;
    int wm = (w & 1) * 64, wn = (w >> 1) * 64;
    int lm = l & 15, quad = l >> 4;

    f32x4 acc[4][4] = {};

    for (int k0 = 0; k0 < K; k0 += 32) {
#pragma unroll
        for (int it = 0; it < 2; ++it) {
            int L = tid + it * 256;          // 0..511
            int row = L >> 2;                // 0..127
            int ch = (L & 3) * 8;            // 0,8,16,24
            int ga = bm + row; if (ga > M - 1) ga = M - 1;
            *(uint4*)&As[row][ch] = *(const uint4*)(A + (size_t)ga * K + k0 + ch);
            *(uint4*)&Bs[row][ch] = *(const uint4*)(B + (size_t)(bn + row) * K + k0 + ch);
        }
        __syncthreads();
        bf16x8 af[4], bfr[4];
#pragma unroll
        for (int i = 0; i < 4; ++i) af[i]  = *(const bf16x8*)&As[wm + i * 16 + lm][quad * 8];
#pragma unroll
        for (int j = 0; j < 4; ++j) bfr[j] = *(const bf16x8*)&Bs[wn + j * 16 + lm][quad * 8];
#pragma unroll
        for (int i = 0; i < 4; ++i)
#pragma unroll
            for (int j = 0; j < 4; ++j)
                acc[i][j] = __builtin_amdgcn_mfma_f32_16x16x32_bf16(af[i], bfr[j], acc[i][j], 0, 0, 0);
        __syncthreads();
    }

    float bv[4] = {0.f, 0.f, 0.f, 0.f};
    if (bias) {
#pragma unroll
        for (int j = 0; j < 4; ++j) bv[j] = bias[bn + wn + j * 16 + lm];
    }
#pragma unroll
    for (int i = 0; i < 4; ++i) {
#pragma unroll
        for (int r = 0; r < 4; ++r) {
            int row = bm + wm + i * 16 + quad * 4 + r;
            if (row < M) {
#pragma unroll
                for (int j = 0; j < 4; ++j) {
                    int col = bn + wn + j * 16 + lm;
                    float v = acc[i][j][r] + bv[j];
                    if (Cf) Cf[(size_t)row * Dout + col] = v;
                    if (Ch) Ch[(size_t)row * Dout + col] = f2b(v);
                }
            }
        }
    }
}

// ---------------- f1/f2 = M @ va, M @ vb (bf16 M, one wave per node) ----------------
__global__ void fvec_bf16(const ushort* __restrict__ Mh, const float* __restrict__ va,
                          const float* __restrict__ vb, float* __restrict__ f1,
                          float* __restrict__ f2, int d) {
    int n = blockIdx.x;
    int lane = threadIdx.x;
    const ushort* row = Mh + (size_t)n * d;
    float s1 = 0.f, s2 = 0.f;
    for (int k = lane; k < d; k += 64) {
        float m = b2f(row[k]);
        s1 += m * va[k];
        s2 += m * vb[k];
    }
#pragma unroll
    for (int off = 32; off > 0; off >>= 1) {
        s1 += __shfl_xor(s1, off);
        s2 += __shfl_xor(s2, off);
    }
    if (lane == 0) { f1[n] = s1; f2[n] = s2; }
}

// ---------------- edge softmax of sigmoid(logits), one wave per row ----------------
__global__ void att_kernel(const int* __restrict__ rp, const int* __restrict__ col_s,
                           const float* __restrict__ a_s, const float* __restrict__ f1,
                           const float* __restrict__ f2, float* __restrict__ att) {
    int r = blockIdx.x;
    int lane = threadIdx.x;
    int beg = rp[r], end = rp[r + 1];
    if (beg == end) return;
    float fr = f1[r];
    float m = -1e30f;
    for (int j = beg + lane; j < end; j += 64) {
        float x = a_s[j] * (fr + f2[col_s[j]]);
        float v = 1.f / (1.f + __expf(-x));
        att[j] = v;
        m = fmaxf(m, v);
    }
#pragma unroll
    for (int off = 32; off > 0; off >>= 1) m = fmaxf(m, __shfl_xor(m, off));
    float s = 0.f;
    for (int j = beg + lane; j < end; j += 64) {
        float e = __expf(att[j] - m);
        att[j] = e;
        s += e;
    }
#pragma unroll
    for (int off = 32; off > 0; off >>= 1) s += __shfl_xor(s, off);
    float inv = 1.f / s;
    for (int j = beg + lane; j < end; j += 64) att[j] *= inv;
}

// ---------------- SpMM (CSR gather, bf16 features, fp32 accumulate) ----------------
// lanes_per_row = d/4; each lane owns a ushort4 (4 bf16) chunk of the feature dim.
// Optional dual output: bf16 (Oh) and fp32 (Of).
__global__ void spmm_bf16(const int* __restrict__ rp, const int* __restrict__ col_s,
                          const float* __restrict__ att, const ushort* __restrict__ H,
                          ushort* __restrict__ Oh, float* __restrict__ Of,
                          int d4, int rows_per_block, int N) {
    int tid = threadIdx.x;
    int r = blockIdx.x * rows_per_block + tid / d4;
    int lane = tid % d4;
    if (r >= N) return;
    int beg = rp[r], end = rp[r + 1];
    float4 acc = make_float4(0.f, 0.f, 0.f, 0.f);
    const ushort4* H4 = (const ushort4*)H;
    for (int j = beg; j < end; ++j) {
        int c = col_s[j];
        float wgt = att[j];
        ushort4 h = H4[(size_t)c * d4 + lane];
        acc.x += wgt * b2f(h.x);
        acc.y += wgt * b2f(h.y);
        acc.z += wgt * b2f(h.z);
        acc.w += wgt * b2f(h.w);
    }
    if (Oh) {
        ushort4 o;
        o.x = f2b(acc.x); o.y = f2b(acc.y); o.z = f2b(acc.z); o.w = f2b(acc.w);
        ((ushort4*)Oh)[(size_t)r * d4 + lane] = o;
    }
    if (Of) ((float4*)Of)[(size_t)r * d4 + lane] = acc;
}

// ---------------- driver ----------------
extern "C" void kernel_launch(void* const* d_in, const int* in_sizes, int n_in,
                              void* d_out, int out_size, void* d_ws, size_t ws_size,
                              hipStream_t stream) {
    const float* X    = (const float*)d_in[0];
    const int*   erow = (const int*)d_in[1];
    const int*   ecol = (const int*)d_in[2];
    const float* aval = (const float*)d_in[3];
    const float* W0   = (const float*)d_in[4];
    const float* b0   = (const float*)d_in[5];
    const float* W1   = (const float*)d_in[6];
    const float* b1   = (const float*)d_in[7];
    const float* v00  = (const float*)d_in[8];
    const float* v01  = (const float*)d_in[9];
    const float* v10  = (const float*)d_in[10];
    const float* v11  = (const float*)d_in[11];

    const int D0 = 512, D1 = 256, D2 = 128;
    const int N = in_sizes[0] / D0;
    const int E = in_sizes[1];
    float* out = (float*)d_out;

    char* ws = (char*)d_ws;
    size_t off = 0;
    auto alloc = [&](size_t bytes) {
        char* p = ws + off;
        off += (bytes + 255) & ~(size_t)255;
        return p;
    };
    ushort* Xh   = (ushort*)alloc((size_t)N * D0 * 2);  // 51.2 MB
    ushort* U1   = (ushort*)alloc((size_t)N * D1 * 2);  // M0h / T1h / T3h
    ushort* U2   = (ushort*)alloc((size_t)N * D1 * 2);  // H1h / T2h
    ushort* M1h  = (ushort*)alloc((size_t)N * D2 * 2);
    ushort* H2h  = (ushort*)alloc((size_t)N * D2 * 2);
    ushort* W0h  = (ushort*)alloc((size_t)D1 * D0 * 2);
    ushort* W1h  = (ushort*)alloc((size_t)D2 * D1 * 2);
    ushort* Wt1h = (ushort*)alloc((size_t)D1 * D2 * 2); // W1^T [256,128]
    ushort* Wt0h = (ushort*)alloc((size_t)D0 * D1 * 2); // W0^T [512,256]
    float* att0  = (float*)alloc((size_t)E * 4);
    float* att1  = (float*)alloc((size_t)E * 4);
    float* a_s   = (float*)alloc((size_t)E * 4);
    float* f1    = (float*)alloc((size_t)N * 4);
    float* f2    = (float*)alloc((size_t)N * 4);
    int* rp      = (int*)alloc(((size_t)N + 1) * 4);
    int* cursor  = (int*)alloc((size_t)N * 4);
    int* col_s   = (int*)alloc((size_t)E * 4);

    // ---- CSR build (rows sorted) ----
    hipMemsetAsync(cursor, 0, (size_t)N * sizeof(int), stream);
    count_kernel<<<(E + 255) / 256, 256, 0, stream>>>(erow, cursor, E);
    scan_kernel<<<1, 1024, 0, stream>>>(cursor, rp, N);
    hipMemsetAsync(cursor, 0, (size_t)N * sizeof(int), stream);
    scatter_kernel<<<(E + 255) / 256, 256, 0, stream>>>(erow, ecol, aval, rp, cursor, col_s, a_s, E);

    // ---- bf16 converts ----
    f2b4_kernel<<<((N * D0 / 4) + 255) / 256, 256, 0, stream>>>(X, Xh, N * D0 / 4);
    f2b4_kernel<<<((D1 * D0 / 4) + 255) / 256, 256, 0, stream>>>(W0, W0h, D1 * D0 / 4);
    f2b4_kernel<<<((D2 * D1 / 4) + 255) / 256, 256, 0, stream>>>(W1, W1h, D2 * D1 / 4);
    transpose_f2b_kernel<<<(D2 * D1 + 255) / 256, 256, 0, stream>>>(W1, Wt1h, D2, D1);
    transpose_f2b_kernel<<<(D1 * D0 + 255) / 256, 256, 0, stream>>>(W0, Wt0h, D1, D0);

    const int gy = (N + 127) / 128;

    // ---- encoder layer 0 ----
    gemm_bf16<<<dim3(D1 / 128, gy), 256, 0, stream>>>(Xh, W0h, b0, nullptr, U1, N, D0, D1);   // M0h
    fvec_bf16<<<N, 64, 0, stream>>>(U1, v00, v01, f1, f2, D1);
    att_kernel<<<N, 64, 0, stream>>>(rp, col_s, a_s, f1, f2, att0);
    spmm_bf16<<<N, 64, 0, stream>>>(rp, col_s, att0, U1, U2, nullptr, D1 / 4, 1, N);          // H1h

    // ---- encoder layer 1 ----
    gemm_bf16<<<dim3(1, gy), 256, 0, stream>>>(U2, W1h, b1, nullptr, M1h, N, D1, D2);         // M1h
    fvec_bf16<<<N, 64, 0, stream>>>(M1h, v10, v11, f1, f2, D2);
    att_kernel<<<N, 64, 0, stream>>>(rp, col_s, a_s, f1, f2, att1);
    // H2 = final_H: bf16 for decoder + fp32 straight into the output tail
    spmm_bf16<<<(N + 1) / 2, 64, 0, stream>>>(rp, col_s, att1, M1h, H2h, out + (size_t)N * D0,
                                              D2 / 4, 2, N);

    // ---- decoder (reordered: out = spmm(att0, spmm(att1, H2@W1)) @ W0) ----
    gemm_bf16<<<dim3(D1 / 128, gy), 256, 0, stream>>>(H2h, Wt1h, nullptr, nullptr, U1, N, D2, D1); // T1h
    spmm_bf16<<<N, 64, 0, stream>>>(rp, col_s, att1, U1, U2, nullptr, D1 / 4, 1, N);               // T2h
    spmm_bf16<<<N, 64, 0, stream>>>(rp, col_s, att0, U2, U1, nullptr, D1 / 4, 1, N);               // T3h
    gemm_bf16<<<dim3(D0 / 128, gy), 256, 0, stream>>>(U1, Wt0h, nullptr, out, nullptr, N, D1, D0); // out
}

// Round 3
// 870.642 us; speedup vs baseline: 2.0168x; 1.4014x over previous
//
#include <hip/hip_runtime.h>
#include <cstdint>
#include <cstddef>

typedef __attribute__((ext_vector_type(8))) short bf16x8;
typedef __attribute__((ext_vector_type(4))) float f32x4;

__device__ __forceinline__ ushort f2b(float f) {
    union { float f; uint32_t u; } v; v.f = f;
    uint32_t r = (v.u + 0x7fffu + ((v.u >> 16) & 1u)) >> 16;
    return (ushort)r;
}
__device__ __forceinline__ float b2f(ushort b) {
    union { uint32_t u; float f; } v; v.u = ((uint32_t)b) << 16;
    return v.f;
}

// ---------------- CSR build ----------------
__global__ void count_kernel(const int* __restrict__ rows, int* __restrict__ counts, int E) {
    int e = blockIdx.x * blockDim.x + threadIdx.x;
    if (e < E) atomicAdd(&counts[rows[e]], 1);
}

// one-block scan: each of 1024 threads serially scans a contiguous chunk
__global__ __launch_bounds__(1024) void scan50k(const int* __restrict__ counts,
                                                int* __restrict__ rp, int n) {
    __shared__ int sm[1024];
    int chunk = (n + 1023) >> 10;
    int base = (int)threadIdx.x * chunk;
    int s = 0;
    for (int i = 0; i < chunk; ++i) {
        int idx = base + i;
        if (idx < n) s += counts[idx];
    }
    sm[threadIdx.x] = s;
    __syncthreads();
    for (int off = 1; off < 1024; off <<= 1) {
        int t = ((int)threadIdx.x >= off) ? sm[threadIdx.x - off] : 0;
        __syncthreads();
        sm[threadIdx.x] += t;
        __syncthreads();
    }
    int run = (threadIdx.x == 0) ? 0 : sm[threadIdx.x - 1];
    for (int i = 0; i < chunk; ++i) {
        int idx = base + i;
        if (idx < n) { run += counts[idx]; rp[idx + 1] = run; }
    }
    if (threadIdx.x == 0) rp[0] = 0;
}

__global__ void scatter_kernel(const int* __restrict__ rows, const int* __restrict__ cols,
                               const float* __restrict__ avals,
                               const int* __restrict__ rp, int* __restrict__ cursor,
                               int* __restrict__ col_s, float* __restrict__ a_s, int E) {
    int e = blockIdx.x * blockDim.x + threadIdx.x;
    if (e < E) {
        int r = rows[e];
        int pos = rp[r] + atomicAdd(&cursor[r], 1);
        col_s[pos] = cols[e];
        a_s[pos]   = avals[e];
    }
}

// ---------------- fp32 -> bf16 converts ----------------
__global__ void f2b4_kernel(const float* __restrict__ src, ushort* __restrict__ dst, int n4) {
    int i = blockIdx.x * blockDim.x + threadIdx.x;
    if (i < n4) {
        float4 v = ((const float4*)src)[i];
        ushort4 o;
        o.x = f2b(v.x); o.y = f2b(v.y); o.z = f2b(v.z); o.w = f2b(v.w);
        ((ushort4*)dst)[i] = o;
    }
}

__global__ void transpose_f2b_kernel(const float* __restrict__ W, ushort* __restrict__ Wt,
                                     int rows, int cols) {
    int idx = blockIdx.x * blockDim.x + threadIdx.x;
    if (idx < rows * cols) {
        int r = idx / cols, c = idx % cols;
        Wt[(size_t)c * rows + r] = f2b(W[idx]);
    }
}

// ---------------- bf16 MFMA NT GEMM ----------------
// C[M,Dout] = A[M,K] @ B[Dout,K]^T + bias.  A,B bf16 row-major (K contiguous).
// 128x128 block tile, 256 threads = 4 waves, each wave a 64x64 quadrant (4x4 MFMA frags).
__global__ __launch_bounds__(256) void gemm_bf16(const ushort* __restrict__ A,
                                                 const ushort* __restrict__ B,
                                                 const float* __restrict__ bias,
                                                 float* __restrict__ Cf,
                                                 ushort* __restrict__ Ch,
                                                 int M, int K, int Dout) {
    __shared__ ushort As[128][40];   // +8 pad breaks bank aliasing on frag reads
    __shared__ ushort Bs[128][40];
    int bm = blockIdx.y * 128, bn = blockIdx.x * 128;
    int tid = threadIdx.x;
    int w = tid >> 6, l = tid & 63;
    int wm = (w & 1) * 64, wn = (w >> 1) * 64;
    int lm = l & 15, quad = l >> 4;

    f32x4 acc[4][4] = {};

    for (int k0 = 0; k0 < K; k0 += 32) {
#pragma unroll
        for (int it = 0; it < 2; ++it) {
            int L = tid + it * 256;          // 0..511
            int row = L >> 2;                // 0..127
            int ch = (L & 3) * 8;            // 0,8,16,24
            int ga = bm + row; if (ga > M - 1) ga = M - 1;
            *(uint4*)&As[row][ch] = *(const uint4*)(A + (size_t)ga * K + k0 + ch);
            *(uint4*)&Bs[row][ch] = *(const uint4*)(B + (size_t)(bn + row) * K + k0 + ch);
        }
        __syncthreads();
        bf16x8 af[4], bfr[4];
#pragma unroll
        for (int i = 0; i < 4; ++i) af[i]  = *(const bf16x8*)&As[wm + i * 16 + lm][quad * 8];
#pragma unroll
        for (int j = 0; j < 4; ++j) bfr[j] = *(const bf16x8*)&Bs[wn + j * 16 + lm][quad * 8];
#pragma unroll
        for (int i = 0; i < 4; ++i)
#pragma unroll
            for (int j = 0; j < 4; ++j)
                acc[i][j] = __builtin_amdgcn_mfma_f32_16x16x32_bf16(af[i], bfr[j], acc[i][j], 0, 0, 0);
        __syncthreads();
    }

    float bv[4] = {0.f, 0.f, 0.f, 0.f};
    if (bias) {
#pragma unroll
        for (int j = 0; j < 4; ++j) bv[j] = bias[bn + wn + j * 16 + lm];
    }
#pragma unroll
    for (int i = 0; i < 4; ++i) {
#pragma unroll
        for (int r = 0; r < 4; ++r) {
            int row = bm + wm + i * 16 + quad * 4 + r;
            if (row < M) {
#pragma unroll
                for (int j = 0; j < 4; ++j) {
                    int col = bn + wn + j * 16 + lm;
                    float v = acc[i][j][r] + bv[j];
                    if (Cf) Cf[(size_t)row * Dout + col] = v;
                    if (Ch) Ch[(size_t)row * Dout + col] = f2b(v);
                }
            }
        }
    }
}

// ---------------- f1/f2 = M @ va, M @ vb (bf16 M, one wave per node) ----------------
__global__ void fvec_bf16(const ushort* __restrict__ Mh, const float* __restrict__ va,
                          const float* __restrict__ vb, float* __restrict__ f1,
                          float* __restrict__ f2, int d) {
    int n = blockIdx.x;
    int lane = threadIdx.x;
    const ushort* row = Mh + (size_t)n * d;
    float s1 = 0.f, s2 = 0.f;
    for (int k = lane; k < d; k += 64) {
        float m = b2f(row[k]);
        s1 += m * va[k];
        s2 += m * vb[k];
    }
#pragma unroll
    for (int off = 32; off > 0; off >>= 1) {
        s1 += __shfl_xor(s1, off);
        s2 += __shfl_xor(s2, off);
    }
    if (lane == 0) { f1[n] = s1; f2[n] = s2; }
}

// ---------------- edge softmax of sigmoid(logits), one wave per row ----------------
__global__ void att_kernel(const int* __restrict__ rp, const int* __restrict__ col_s,
                           const float* __restrict__ a_s, const float* __restrict__ f1,
                           const float* __restrict__ f2, float* __restrict__ att) {
    int r = blockIdx.x;
    int lane = threadIdx.x;
    int beg = rp[r], end = rp[r + 1];
    if (beg == end) return;
    float fr = f1[r];
    float m = -1e30f;
    for (int j = beg + lane; j < end; j += 64) {
        float x = a_s[j] * (fr + f2[col_s[j]]);
        float v = 1.f / (1.f + __expf(-x));
        att[j] = v;
        m = fmaxf(m, v);
    }
#pragma unroll
    for (int off = 32; off > 0; off >>= 1) m = fmaxf(m, __shfl_xor(m, off));
    float s = 0.f;
    for (int j = beg + lane; j < end; j += 64) {
        float e = __expf(att[j] - m);
        att[j] = e;
        s += e;
    }
#pragma unroll
    for (int off = 32; off > 0; off >>= 1) s += __shfl_xor(s, off);
    float inv = 1.f / s;
    for (int j = beg + lane; j < end; j += 64) att[j] *= inv;
}

// ---------------- SpMM (CSR gather, bf16 features, fp32 accumulate) ----------------
// 256 threads; d4 lanes per row (d4=32 for d=128); rows_per_block = 256/d4.
// Edge loop unrolled x4 for memory-level parallelism. Optional bias (per-feature),
// optional bf16 (Oh) and fp32 (Of) outputs.
__global__ __launch_bounds__(256) void spmm_bf16(const int* __restrict__ rp,
                                                 const int* __restrict__ col_s,
                                                 const float* __restrict__ att,
                                                 const ushort* __restrict__ H,
                                                 const float* __restrict__ bias,
                                                 ushort* __restrict__ Oh,
                                                 float* __restrict__ Of,
                                                 int d4, int N) {
    int tid = threadIdx.x;
    int rpb = 256 / d4;
    int r = blockIdx.x * rpb + tid / d4;
    int lane = tid % d4;
    if (r >= N) return;
    int beg = rp[r], end = rp[r + 1];
    float4 acc = make_float4(0.f, 0.f, 0.f, 0.f);
    const ushort4* H4 = (const ushort4*)H;
    int j = beg;
    for (; j + 4 <= end; j += 4) {
        int c0 = col_s[j], c1 = col_s[j + 1], c2 = col_s[j + 2], c3 = col_s[j + 3];
        float w0 = att[j], w1 = att[j + 1], w2 = att[j + 2], w3 = att[j + 3];
        ushort4 h0 = H4[(size_t)c0 * d4 + lane];
        ushort4 h1 = H4[(size_t)c1 * d4 + lane];
        ushort4 h2 = H4[(size_t)c2 * d4 + lane];
        ushort4 h3 = H4[(size_t)c3 * d4 + lane];
        acc.x += w0 * b2f(h0.x) + w1 * b2f(h1.x) + w2 * b2f(h2.x) + w3 * b2f(h3.x);
        acc.y += w0 * b2f(h0.y) + w1 * b2f(h1.y) + w2 * b2f(h2.y) + w3 * b2f(h3.y);
        acc.z += w0 * b2f(h0.z) + w1 * b2f(h1.z) + w2 * b2f(h2.z) + w3 * b2f(h3.z);
        acc.w += w0 * b2f(h0.w) + w1 * b2f(h1.w) + w2 * b2f(h2.w) + w3 * b2f(h3.w);
    }
    for (; j < end; ++j) {
        int c = col_s[j];
        float wgt = att[j];
        ushort4 h = H4[(size_t)c * d4 + lane];
        acc.x += wgt * b2f(h.x);
        acc.y += wgt * b2f(h.y);
        acc.z += wgt * b2f(h.z);
        acc.w += wgt * b2f(h.w);
    }
    if (bias) {
        acc.x += bias[lane * 4 + 0];
        acc.y += bias[lane * 4 + 1];
        acc.z += bias[lane * 4 + 2];
        acc.w += bias[lane * 4 + 3];
    }
    if (Oh) {
        ushort4 o;
        o.x = f2b(acc.x); o.y = f2b(acc.y); o.z = f2b(acc.z); o.w = f2b(acc.w);
        ((ushort4*)Oh)[(size_t)r * d4 + lane] = o;
    }
    if (Of) ((float4*)Of)[(size_t)r * d4 + lane] = acc;
}

// ---------------- driver ----------------
// Algebra (all ops linear; softmax rows sum to 1 so bias commutes through spmm):
//   M0 = X@W0^T + b0                         [N,256]  (needed for att0 logits)
//   P  = M0@W1^T                             [N,128]
//   M1 = spmm(att0, P) + b1                  [N,128]  (== H1@W1^T + b1)
//   H2 = spmm(att1, M1)                      [N,128]  (final_H)
//   out = spmm(att0, spmm(att1, H2)) @ (W1@W0)        [N,512]
extern "C" void kernel_launch(void* const* d_in, const int* in_sizes, int n_in,
                              void* d_out, int out_size, void* d_ws, size_t ws_size,
                              hipStream_t stream) {
    const float* X    = (const float*)d_in[0];
    const int*   erow = (const int*)d_in[1];
    const int*   ecol = (const int*)d_in[2];
    const float* aval = (const float*)d_in[3];
    const float* W0   = (const float*)d_in[4];
    const float* b0   = (const float*)d_in[5];
    const float* W1   = (const float*)d_in[6];
    const float* b1   = (const float*)d_in[7];
    const float* v00  = (const float*)d_in[8];
    const float* v01  = (const float*)d_in[9];
    const float* v10  = (const float*)d_in[10];
    const float* v11  = (const float*)d_in[11];

    const int D0 = 512, D1 = 256, D2 = 128;
    const int N = in_sizes[0] / D0;
    const int E = in_sizes[1];
    float* out = (float*)d_out;

    char* ws = (char*)d_ws;
    size_t off = 0;
    auto alloc = [&](size_t bytes) {
        char* p = ws + off;
        off += (bytes + 255) & ~(size_t)255;
        return p;
    };
    ushort* Xh   = (ushort*)alloc((size_t)N * D0 * 2);
    ushort* M0h  = (ushort*)alloc((size_t)N * D1 * 2);
    ushort* Ph   = (ushort*)alloc((size_t)N * D2 * 2);  // P / S1
    ushort* M1h  = (ushort*)alloc((size_t)N * D2 * 2);
    ushort* H2h  = (ushort*)alloc((size_t)N * D2 * 2);
    ushort* S0h  = (ushort*)alloc((size_t)N * D2 * 2);
    ushort* W0h  = (ushort*)alloc((size_t)D1 * D0 * 2); // [256,512]
    ushort* W1h  = (ushort*)alloc((size_t)D2 * D1 * 2); // [128,256]
    ushort* Wt0h = (ushort*)alloc((size_t)D0 * D1 * 2); // W0^T [512,256]
    ushort* WfTh = (ushort*)alloc((size_t)D0 * D2 * 2); // (W1@W0)^T [512,128]
    float* att0  = (float*)alloc((size_t)E * 4);
    float* att1  = (float*)alloc((size_t)E * 4);
    float* a_s   = (float*)alloc((size_t)E * 4);
    float* f1    = (float*)alloc((size_t)N * 4);
    float* f2    = (float*)alloc((size_t)N * 4);
    int* rp      = (int*)alloc(((size_t)N + 1) * 4);
    int* cursor  = (int*)alloc((size_t)N * 4);
    int* col_s   = (int*)alloc((size_t)E * 4);

    // ---- CSR build ----
    hipMemsetAsync(cursor, 0, (size_t)N * sizeof(int), stream);
    count_kernel<<<(E + 255) / 256, 256, 0, stream>>>(erow, cursor, E);
    scan50k<<<1, 1024, 0, stream>>>(cursor, rp, N);
    hipMemsetAsync(cursor, 0, (size_t)N * sizeof(int), stream);
    scatter_kernel<<<(E + 255) / 256, 256, 0, stream>>>(erow, ecol, aval, rp, cursor, col_s, a_s, E);

    // ---- bf16 converts ----
    f2b4_kernel<<<((N * D0 / 4) + 255) / 256, 256, 0, stream>>>(X, Xh, N * D0 / 4);
    f2b4_kernel<<<((D1 * D0 / 4) + 255) / 256, 256, 0, stream>>>(W0, W0h, D1 * D0 / 4);
    f2b4_kernel<<<((D2 * D1 / 4) + 255) / 256, 256, 0, stream>>>(W1, W1h, D2 * D1 / 4);
    transpose_f2b_kernel<<<(D1 * D0 + 255) / 256, 256, 0, stream>>>(W0, Wt0h, D1, D0);

    // ---- fused decoder weight: WfT[512,128] = (W1@W0)^T = gemm_nt(Wt0h, W1h) ----
    gemm_bf16<<<dim3(1, 4), 256, 0, stream>>>(Wt0h, W1h, nullptr, nullptr, WfTh, D0, D1, D2);

    const int gy = (N + 127) / 128;
    const int sgrid = (N + 7) / 8;   // spmm: 8 rows/block at d4=32

    // ---- encoder ----
    gemm_bf16<<<dim3(D1 / 128, gy), 256, 0, stream>>>(Xh, W0h, b0, nullptr, M0h, N, D0, D1); // M0
    fvec_bf16<<<N, 64, 0, stream>>>(M0h, v00, v01, f1, f2, D1);
    att_kernel<<<N, 64, 0, stream>>>(rp, col_s, a_s, f1, f2, att0);
    gemm_bf16<<<dim3(1, gy), 256, 0, stream>>>(M0h, W1h, nullptr, nullptr, Ph, N, D1, D2);   // P
    spmm_bf16<<<sgrid, 256, 0, stream>>>(rp, col_s, att0, Ph, b1, M1h, nullptr, D2 / 4, N);  // M1
    fvec_bf16<<<N, 64, 0, stream>>>(M1h, v10, v11, f1, f2, D2);
    att_kernel<<<N, 64, 0, stream>>>(rp, col_s, a_s, f1, f2, att1);
    // H2 = final_H: bf16 for decoder + fp32 straight into output tail
    spmm_bf16<<<sgrid, 256, 0, stream>>>(rp, col_s, att1, M1h, nullptr, H2h,
                                         out + (size_t)N * D0, D2 / 4, N);

    // ---- decoder (fully commuted) ----
    spmm_bf16<<<sgrid, 256, 0, stream>>>(rp, col_s, att1, H2h, nullptr, Ph, nullptr, D2 / 4, N);  // S1
    spmm_bf16<<<sgrid, 256, 0, stream>>>(rp, col_s, att0, Ph, nullptr, S0h, nullptr, D2 / 4, N);  // S0
    gemm_bf16<<<dim3(D0 / 128, gy), 256, 0, stream>>>(S0h, WfTh, nullptr, out, nullptr, N, D2, D0);
}

// Round 4
// 693.372 us; speedup vs baseline: 2.5324x; 1.2557x over previous
//
#include <hip/hip_runtime.h>
#include <cstdint>
#include <cstddef>

typedef __attribute__((ext_vector_type(8))) short bf16x8;
typedef __attribute__((ext_vector_type(4))) float f32x4;

__device__ __forceinline__ ushort f2b(float f) {
    union { float f; uint32_t u; } v; v.f = f;
    uint32_t r = (v.u + 0x7fffu + ((v.u >> 16) & 1u)) >> 16;
    return (ushort)r;
}
__device__ __forceinline__ float b2f(ushort b) {
    union { uint32_t u; float f; } v; v.u = ((uint32_t)b) << 16;
    return v.f;
}

// ================= CSR build v2: two-level bucket sort =================
// Bucket = row >> 7 (128 rows/bucket). Requires N <= 65536 (row/col packed
// into 16 bits each) — problem has N = 50000.

// 1) bucket histogram (LDS-aggregated)
__global__ __launch_bounds__(256) void hist_kernel(const int* __restrict__ rows,
                                                   int* __restrict__ bhist, int E, int nb) {
    __shared__ int h[512];
    for (int i = threadIdx.x; i < nb; i += 256) h[i] = 0;
    __syncthreads();
    int stride = gridDim.x * blockDim.x;
    for (int e = blockIdx.x * blockDim.x + threadIdx.x; e < E; e += stride)
        atomicAdd(&h[rows[e] >> 7], 1);
    __syncthreads();
    for (int i = threadIdx.x; i < nb; i += 256)
        if (h[i]) atomicAdd(&bhist[i], h[i]);
}

// 2) scan bucket counts (nb <= 512); also init global cursors and rp[N]
__global__ __launch_bounds__(512) void scan512(const int* __restrict__ bhist,
                                               int* __restrict__ boff, int* __restrict__ gcur,
                                               int* __restrict__ rp, int nb, int E, int N) {
    __shared__ int sm[512];
    int v = ((int)threadIdx.x < nb) ? bhist[threadIdx.x] : 0;
    sm[threadIdx.x] = v;
    __syncthreads();
    for (int off = 1; off < 512; off <<= 1) {
        int t = ((int)threadIdx.x >= off) ? sm[threadIdx.x - off] : 0;
        __syncthreads();
        sm[threadIdx.x] += t;
        __syncthreads();
    }
    if ((int)threadIdx.x < nb) {
        int e0 = sm[threadIdx.x] - v;   // exclusive prefix
        boff[threadIdx.x] = e0;
        gcur[threadIdx.x] = e0;
    }
    if (threadIdx.x == 0) { boff[nb] = E; rp[N] = E; }
}

// 3) bin edges into bucket-contiguous tmp (packed uint2)
__global__ __launch_bounds__(256) void binpass(const int* __restrict__ rows,
                                               const int* __restrict__ cols,
                                               const float* __restrict__ avals,
                                               int* __restrict__ gcur,
                                               uint2* __restrict__ tmp, int E, int nb) {
    __shared__ int hist[512];
    __shared__ int base[512];
    int e0 = blockIdx.x * 4096;
    int nE = min(4096, E - e0);
    for (int i = threadIdx.x; i < nb; i += 256) hist[i] = 0;
    __syncthreads();
    for (int i = threadIdx.x; i < nE; i += 256)
        atomicAdd(&hist[rows[e0 + i] >> 7], 1);
    __syncthreads();
    for (int i = threadIdx.x; i < nb; i += 256) {
        int c = hist[i];
        if (c) base[i] = atomicAdd(&gcur[i], c);
        hist[i] = 0;
    }
    __syncthreads();
    for (int i = threadIdx.x; i < nE; i += 256) {
        int r = rows[e0 + i];
        int b = r >> 7;
        int loc = atomicAdd(&hist[b], 1);
        uint2 t;
        t.x = ((uint32_t)r << 16) | (uint32_t)cols[e0 + i];
        t.y = __float_as_uint(avals[e0 + i]);
        tmp[base[b] + loc] = t;
    }
}

// 4) per-bucket: row counts -> rp, then scatter col_s / a_s (L2-hot region)
__global__ __launch_bounds__(256) void bucketpass(const uint2* __restrict__ tmp,
                                                  const int* __restrict__ boff,
                                                  int* __restrict__ rp,
                                                  int* __restrict__ col_s,
                                                  float* __restrict__ a_s, int N) {
    __shared__ int cnt[128];
    __shared__ int pre[128];
    int b = blockIdx.x;
    int r0 = b << 7;
    int nr = min(128, N - r0);
    int t0 = boff[b], t1 = boff[b + 1];
    if ((int)threadIdx.x < 128) cnt[threadIdx.x] = 0;
    __syncthreads();
    for (int i = t0 + (int)threadIdx.x; i < t1; i += 256)
        atomicAdd(&cnt[(tmp[i].x >> 16) - r0], 1);
    __syncthreads();
    if ((int)threadIdx.x < 128) pre[threadIdx.x] = cnt[threadIdx.x];
    __syncthreads();
    for (int off = 1; off < 128; off <<= 1) {
        int t = ((int)threadIdx.x >= off && (int)threadIdx.x < 128) ? pre[threadIdx.x - off] : 0;
        __syncthreads();
        if ((int)threadIdx.x < 128) pre[threadIdx.x] += t;
        __syncthreads();
    }
    if ((int)threadIdx.x < nr) {
        int ex = pre[threadIdx.x] - cnt[threadIdx.x];   // exclusive prefix
        rp[r0 + threadIdx.x] = t0 + ex;
        cnt[threadIdx.x] = t0 + ex;                     // becomes running cursor
    }
    __syncthreads();
    for (int i = t0 + (int)threadIdx.x; i < t1; i += 256) {
        uint2 t = tmp[i];
        int lr = (int)(t.x >> 16) - r0;
        int pos = atomicAdd(&cnt[lr], 1);
        col_s[pos] = (int)(t.x & 0xffffu);
        a_s[pos] = __uint_as_float(t.y);
    }
}

// ---------------- fp32 -> bf16 converts ----------------
__global__ void f2b4_kernel(const float* __restrict__ src, ushort* __restrict__ dst, int n4) {
    int i = blockIdx.x * blockDim.x + threadIdx.x;
    if (i < n4) {
        float4 v = ((const float4*)src)[i];
        ushort4 o;
        o.x = f2b(v.x); o.y = f2b(v.y); o.z = f2b(v.z); o.w = f2b(v.w);
        ((ushort4*)dst)[i] = o;
    }
}

__global__ void transpose_f2b_kernel(const float* __restrict__ W, ushort* __restrict__ Wt,
                                     int rows, int cols) {
    int idx = blockIdx.x * blockDim.x + threadIdx.x;
    if (idx < rows * cols) {
        int r = idx / cols, c = idx % cols;
        Wt[(size_t)c * rows + r] = f2b(W[idx]);
    }
}

// ---------------- bf16 MFMA NT GEMM ----------------
// C[M,Dout] = A[M,K] @ B[Dout,K]^T + bias.  A,B bf16 row-major (K contiguous).
// 128x128 block tile, 256 threads = 4 waves, each wave a 64x64 quadrant (4x4 MFMA frags).
__global__ __launch_bounds__(256) void gemm_bf16(const ushort* __restrict__ A,
                                                 const ushort* __restrict__ B,
                                                 const float* __restrict__ bias,
                                                 float* __restrict__ Cf,
                                                 ushort* __restrict__ Ch,
                                                 int M, int K, int Dout) {
    __shared__ ushort As[128][40];   // +8 pad breaks bank aliasing on frag reads
    __shared__ ushort Bs[128][40];
    int bm = blockIdx.y * 128, bn = blockIdx.x * 128;
    int tid = threadIdx.x;
    int w = tid >> 6, l = tid & 63;
    int wm = (w & 1) * 64, wn = (w >> 1) * 64;
    int lm = l & 15, quad = l >> 4;

    f32x4 acc[4][4] = {};

    for (int k0 = 0; k0 < K; k0 += 32) {
#pragma unroll
        for (int it = 0; it < 2; ++it) {
            int L = tid + it * 256;          // 0..511
            int row = L >> 2;                // 0..127
            int ch = (L & 3) * 8;            // 0,8,16,24
            int ga = bm + row; if (ga > M - 1) ga = M - 1;
            *(uint4*)&As[row][ch] = *(const uint4*)(A + (size_t)ga * K + k0 + ch);
            *(uint4*)&Bs[row][ch] = *(const uint4*)(B + (size_t)(bn + row) * K + k0 + ch);
        }
        __syncthreads();
        bf16x8 af[4], bfr[4];
#pragma unroll
        for (int i = 0; i < 4; ++i) af[i]  = *(const bf16x8*)&As[wm + i * 16 + lm][quad * 8];
#pragma unroll
        for (int j = 0; j < 4; ++j) bfr[j] = *(const bf16x8*)&Bs[wn + j * 16 + lm][quad * 8];
#pragma unroll
        for (int i = 0; i < 4; ++i)
#pragma unroll
            for (int j = 0; j < 4; ++j)
                acc[i][j] = __builtin_amdgcn_mfma_f32_16x16x32_bf16(af[i], bfr[j], acc[i][j], 0, 0, 0);
        __syncthreads();
    }

    float bv[4] = {0.f, 0.f, 0.f, 0.f};
    if (bias) {
#pragma unroll
        for (int j = 0; j < 4; ++j) bv[j] = bias[bn + wn + j * 16 + lm];
    }
#pragma unroll
    for (int i = 0; i < 4; ++i) {
#pragma unroll
        for (int r = 0; r < 4; ++r) {
            int row = bm + wm + i * 16 + quad * 4 + r;
            if (row < M) {
#pragma unroll
                for (int j = 0; j < 4; ++j) {
                    int col = bn + wn + j * 16 + lm;
                    float v = acc[i][j][r] + bv[j];
                    if (Cf) Cf[(size_t)row * Dout + col] = v;
                    if (Ch) Ch[(size_t)row * Dout + col] = f2b(v);
                }
            }
        }
    }
}

// ---------------- f1/f2 = M @ va, M @ vb (bf16 M, one wave per node) ----------------
__global__ void fvec_bf16(const ushort* __restrict__ Mh, const float* __restrict__ va,
                          const float* __restrict__ vb, float* __restrict__ f1,
                          float* __restrict__ f2, int d) {
    int n = blockIdx.x;
    int lane = threadIdx.x;
    const ushort* row = Mh + (size_t)n * d;
    float s1 = 0.f, s2 = 0.f;
    for (int k = lane; k < d; k += 64) {
        float m = b2f(row[k]);
        s1 += m * va[k];
        s2 += m * vb[k];
    }
#pragma unroll
    for (int off = 32; off > 0; off >>= 1) {
        s1 += __shfl_xor(s1, off);
        s2 += __shfl_xor(s2, off);
    }
    if (lane == 0) { f1[n] = s1; f2[n] = s2; }
}

// ---------------- edge softmax of sigmoid(logits), one wave per row ----------------
__global__ void att_kernel(const int* __restrict__ rp, const int* __restrict__ col_s,
                           const float* __restrict__ a_s, const float* __restrict__ f1,
                           const float* __restrict__ f2, float* __restrict__ att) {
    int r = blockIdx.x;
    int lane = threadIdx.x;
    int beg = rp[r], end = rp[r + 1];
    if (beg == end) return;
    float fr = f1[r];
    float m = -1e30f;
    for (int j = beg + lane; j < end; j += 64) {
        float x = a_s[j] * (fr + f2[col_s[j]]);
        float v = 1.f / (1.f + __expf(-x));
        att[j] = v;
        m = fmaxf(m, v);
    }
#pragma unroll
    for (int off = 32; off > 0; off >>= 1) m = fmaxf(m, __shfl_xor(m, off));
    float s = 0.f;
    for (int j = beg + lane; j < end; j += 64) {
        float e = __expf(att[j] - m);
        att[j] = e;
        s += e;
    }
#pragma unroll
    for (int off = 32; off > 0; off >>= 1) s += __shfl_xor(s, off);
    float inv = 1.f / s;
    for (int j = beg + lane; j < end; j += 64) att[j] *= inv;
}

// ---------------- SpMM (CSR gather, bf16 features, fp32 accumulate) ----------------
__global__ __launch_bounds__(256) void spmm_bf16(const int* __restrict__ rp,
                                                 const int* __restrict__ col_s,
                                                 const float* __restrict__ att,
                                                 const ushort* __restrict__ H,
                                                 const float* __restrict__ bias,
                                                 ushort* __restrict__ Oh,
                                                 float* __restrict__ Of,
                                                 int d4, int N) {
    int tid = threadIdx.x;
    int rpb = 256 / d4;
    int r = blockIdx.x * rpb + tid / d4;
    int lane = tid % d4;
    if (r >= N) return;
    int beg = rp[r], end = rp[r + 1];
    float4 acc = make_float4(0.f, 0.f, 0.f, 0.f);
    const ushort4* H4 = (const ushort4*)H;
    int j = beg;
    for (; j + 4 <= end; j += 4) {
        int c0 = col_s[j], c1 = col_s[j + 1], c2 = col_s[j + 2], c3 = col_s[j + 3];
        float w0 = att[j], w1 = att[j + 1], w2 = att[j + 2], w3 = att[j + 3];
        ushort4 h0 = H4[(size_t)c0 * d4 + lane];
        ushort4 h1 = H4[(size_t)c1 * d4 + lane];
        ushort4 h2 = H4[(size_t)c2 * d4 + lane];
        ushort4 h3 = H4[(size_t)c3 * d4 + lane];
        acc.x += w0 * b2f(h0.x) + w1 * b2f(h1.x) + w2 * b2f(h2.x) + w3 * b2f(h3.x);
        acc.y += w0 * b2f(h0.y) + w1 * b2f(h1.y) + w2 * b2f(h2.y) + w3 * b2f(h3.y);
        acc.z += w0 * b2f(h0.z) + w1 * b2f(h1.z) + w2 * b2f(h2.z) + w3 * b2f(h3.z);
        acc.w += w0 * b2f(h0.w) + w1 * b2f(h1.w) + w2 * b2f(h2.w) + w3 * b2f(h3.w);
    }
    for (; j < end; ++j) {
        int c = col_s[j];
        float wgt = att[j];
        ushort4 h = H4[(size_t)c * d4 + lane];
        acc.x += wgt * b2f(h.x);
        acc.y += wgt * b2f(h.y);
        acc.z += wgt * b2f(h.z);
        acc.w += wgt * b2f(h.w);
    }
    if (bias) {
        acc.x += bias[lane * 4 + 0];
        acc.y += bias[lane * 4 + 1];
        acc.z += bias[lane * 4 + 2];
        acc.w += bias[lane * 4 + 3];
    }
    if (Oh) {
        ushort4 o;
        o.x = f2b(acc.x); o.y = f2b(acc.y); o.z = f2b(acc.z); o.w = f2b(acc.w);
        ((ushort4*)Oh)[(size_t)r * d4 + lane] = o;
    }
    if (Of) ((float4*)Of)[(size_t)r * d4 + lane] = acc;
}

// ---------------- driver ----------------
// Algebra (all ops linear; softmax rows sum to 1 so bias commutes through spmm):
//   M0 = X@W0^T + b0                         [N,256]  (needed for att0 logits)
//   P  = M0@W1^T                             [N,128]
//   M1 = spmm(att0, P) + b1                  [N,128]  (== H1@W1^T + b1)
//   H2 = spmm(att1, M1)                      [N,128]  (final_H)
//   out = spmm(att0, spmm(att1, H2)) @ (W1@W0)        [N,512]
extern "C" void kernel_launch(void* const* d_in, const int* in_sizes, int n_in,
                              void* d_out, int out_size, void* d_ws, size_t ws_size,
                              hipStream_t stream) {
    const float* X    = (const float*)d_in[0];
    const int*   erow = (const int*)d_in[1];
    const int*   ecol = (const int*)d_in[2];
    const float* aval = (const float*)d_in[3];
    const float* W0   = (const float*)d_in[4];
    const float* b0   = (const float*)d_in[5];
    const float* W1   = (const float*)d_in[6];
    const float* b1   = (const float*)d_in[7];
    const float* v00  = (const float*)d_in[8];
    const float* v01  = (const float*)d_in[9];
    const float* v10  = (const float*)d_in[10];
    const float* v11  = (const float*)d_in[11];

    const int D0 = 512, D1 = 256, D2 = 128;
    const int N = in_sizes[0] / D0;
    const int E = in_sizes[1];
    const int NB = (N + 127) / 128;       // buckets (<=512 since N<=65536)
    float* out = (float*)d_out;

    char* ws = (char*)d_ws;
    size_t off = 0;
    auto alloc = [&](size_t bytes) {
        char* p = ws + off;
        off += (bytes + 255) & ~(size_t)255;
        return p;
    };
    ushort* Xh   = (ushort*)alloc((size_t)N * D0 * 2);
    ushort* M0h  = (ushort*)alloc((size_t)N * D1 * 2);
    ushort* Ph   = (ushort*)alloc((size_t)N * D2 * 2);  // P / S1
    ushort* M1h  = (ushort*)alloc((size_t)N * D2 * 2);
    ushort* H2h  = (ushort*)alloc((size_t)N * D2 * 2);
    ushort* S0h  = (ushort*)alloc((size_t)N * D2 * 2);
    ushort* W0h  = (ushort*)alloc((size_t)D1 * D0 * 2); // [256,512]
    ushort* W1h  = (ushort*)alloc((size_t)D2 * D1 * 2); // [128,256]
    ushort* Wt0h = (ushort*)alloc((size_t)D0 * D1 * 2); // W0^T [512,256]
    ushort* WfTh = (ushort*)alloc((size_t)D0 * D2 * 2); // (W1@W0)^T [512,128]
    float* att0  = (float*)alloc((size_t)E * 4);
    float* att1  = (float*)alloc((size_t)E * 4);
    float* a_s   = (float*)alloc((size_t)E * 4);
    float* f1    = (float*)alloc((size_t)N * 4);
    float* f2    = (float*)alloc((size_t)N * 4);
    int* rp      = (int*)alloc(((size_t)N + 1) * 4);
    int* col_s   = (int*)alloc((size_t)E * 4);
    uint2* tmp   = (uint2*)alloc((size_t)E * 8);
    int* bhist   = (int*)alloc(512 * 4);
    int* boff    = (int*)alloc(513 * 4);
    int* gcur    = (int*)alloc(512 * 4);

    // ---- CSR build v2 ----
    hipMemsetAsync(bhist, 0, 512 * sizeof(int), stream);
    hist_kernel<<<256, 256, 0, stream>>>(erow, bhist, E, NB);
    scan512<<<1, 512, 0, stream>>>(bhist, boff, gcur, rp, NB, E, N);
    binpass<<<(E + 4095) / 4096, 256, 0, stream>>>(erow, ecol, aval, gcur, tmp, E, NB);
    bucketpass<<<NB, 256, 0, stream>>>(tmp, boff, rp, col_s, a_s, N);

    // ---- bf16 converts ----
    f2b4_kernel<<<((N * D0 / 4) + 255) / 256, 256, 0, stream>>>(X, Xh, N * D0 / 4);
    f2b4_kernel<<<((D1 * D0 / 4) + 255) / 256, 256, 0, stream>>>(W0, W0h, D1 * D0 / 4);
    f2b4_kernel<<<((D2 * D1 / 4) + 255) / 256, 256, 0, stream>>>(W1, W1h, D2 * D1 / 4);
    transpose_f2b_kernel<<<(D1 * D0 + 255) / 256, 256, 0, stream>>>(W0, Wt0h, D1, D0);

    // ---- fused decoder weight: WfT[512,128] = (W1@W0)^T = gemm_nt(Wt0h, W1h) ----
    gemm_bf16<<<dim3(1, 4), 256, 0, stream>>>(Wt0h, W1h, nullptr, nullptr, WfTh, D0, D1, D2);

    const int gy = (N + 127) / 128;
    const int sgrid = (N + 7) / 8;   // spmm: 8 rows/block at d4=32

    // ---- encoder ----
    gemm_bf16<<<dim3(D1 / 128, gy), 256, 0, stream>>>(Xh, W0h, b0, nullptr, M0h, N, D0, D1); // M0
    fvec_bf16<<<N, 64, 0, stream>>>(M0h, v00, v01, f1, f2, D1);
    att_kernel<<<N, 64, 0, stream>>>(rp, col_s, a_s, f1, f2, att0);
    gemm_bf16<<<dim3(1, gy), 256, 0, stream>>>(M0h, W1h, nullptr, nullptr, Ph, N, D1, D2);   // P
    spmm_bf16<<<sgrid, 256, 0, stream>>>(rp, col_s, att0, Ph, b1, M1h, nullptr, D2 / 4, N);  // M1
    fvec_bf16<<<N, 64, 0, stream>>>(M1h, v10, v11, f1, f2, D2);
    att_kernel<<<N, 64, 0, stream>>>(rp, col_s, a_s, f1, f2, att1);
    // H2 = final_H: bf16 for decoder + fp32 straight into output tail
    spmm_bf16<<<sgrid, 256, 0, stream>>>(rp, col_s, att1, M1h, nullptr, H2h,
                                         out + (size_t)N * D0, D2 / 4, N);

    // ---- decoder (fully commuted) ----
    spmm_bf16<<<sgrid, 256, 0, stream>>>(rp, col_s, att1, H2h, nullptr, Ph, nullptr, D2 / 4, N);  // S1
    spmm_bf16<<<sgrid, 256, 0, stream>>>(rp, col_s, att0, Ph, nullptr, S0h, nullptr, D2 / 4, N);  // S0
    gemm_bf16<<<dim3(D0 / 128, gy), 256, 0, stream>>>(S0h, WfTh, nullptr, out, nullptr, N, D2, D0);
}